// Round 1
// baseline (60216.083 us; speedup 1.0000x reference)
//
#include <hip/hip_runtime.h>
#include <math.h>

// Problem constants
#define TT 2048
#define HZ 16
#define NBLK 32

// d_out layout (floats): pred | attw | q_gru_n | dec_gru_n | query_n
#define OUT_ATTW   (2048*64*64)            // 8388608
#define OUT_QGRU   (OUT_ATTW + 2048*8*64)  // 9437184
#define OUT_DECGRU (OUT_QGRU + 256)        // 9437440
#define OUT_QN     (OUT_DECGRU + 256)      // 9437696

// d_ws layout (bytes)
#define WSO_FLAGS  0                        // int flags[6144][32] = 786432 B
#define WSO_H2X    786432                   // float[256]
#define WSO_HIDX   787456                   // float[256]
#define WSO_QX     788480                   // float[512]
#define WSO_DECHX  790528                   // float[2][256]
#define WSO_ZEND   792576                   // end of memset region
#define WSO_GIFIX  794624                   // float[2048][768]
#define WSO_HIDFIX (WSO_GIFIX + 2048*768*4)
#define WSO_WQT    (WSO_HIDFIX + 2048*256*4)
#define WSO_W2T    (WSO_WQT + 512*256*4)
#define WSO_DAVA   (WSO_W2T + 64*256*4)
#define WSO_DECH   (WSO_DAVA + 2048*512*4)
#define WSO_FEAT   (WSO_DECH + 2048*256*4)
#define WSO_S      (WSO_FEAT + 2048*832*4)

__device__ __forceinline__ float warp_sum(float v) {
#pragma unroll
  for (int o = 32; o > 0; o >>= 1) v += __shfl_down(v, o, 64);
  return v;
}
__device__ __forceinline__ float warp_max(float v) {
#pragma unroll
  for (int o = 32; o > 0; o >>= 1) v = fmaxf(v, __shfl_down(v, o, 64));
  return v;
}
__device__ __forceinline__ float sigf(float x) { return 1.f / (1.f + __expf(-x)); }
__device__ __forceinline__ float dot4(float4 a, float4 b) {
  return a.x*b.x + a.y*b.y + a.z*b.z + a.w*b.w;
}
__device__ __forceinline__ float aload(const float* p) {
  return __hip_atomic_load(p, __ATOMIC_RELAXED, __HIP_MEMORY_SCOPE_AGENT);
}
__device__ __forceinline__ void astore(float* p, float v) {
  __hip_atomic_store(p, v, __ATOMIC_RELAXED, __HIP_MEMORY_SCOPE_AGENT);
}

// Inter-block barrier: per-phase flag row, one flag per block; wave 0 spins.
__device__ __forceinline__ void gbar(int* flags, int phase, int bid) {
  __syncthreads();
  if (threadIdx.x == 0) {
    __builtin_amdgcn_fence(__ATOMIC_RELEASE, "agent");
    __hip_atomic_store(&flags[phase*NBLK + bid], 1, __ATOMIC_RELAXED,
                       __HIP_MEMORY_SCOPE_AGENT);
  }
  if (threadIdx.x < 64) {
    int l = threadIdx.x;
    int done = 0;
    while (!done) {
      int f = 1;
      if (l < NBLK)
        f = __hip_atomic_load(&flags[phase*NBLK + l], __ATOMIC_RELAXED,
                              __HIP_MEMORY_SCOPE_AGENT);
      done = __all(f != 0);
      if (!done) __builtin_amdgcn_s_sleep(1);
    }
  }
  __syncthreads();
  __builtin_amdgcn_fence(__ATOMIC_ACQUIRE, "agent");
}

// ---------------- transpose of weight_q and dec_out_w ----------------
__global__ void transpose_k(const float* __restrict__ wq,   // [256,512]
                            const float* __restrict__ w2,   // [64,256]
                            float* __restrict__ wqT,        // [512,256]
                            float* __restrict__ w2T) {      // [256,64]
  int g = blockIdx.x * 256 + threadIdx.x;
  if (blockIdx.x < 512) {
    int j = g >> 8, c = g & 255;
    wqT[g] = wq[c * 512 + j];
  } else {
    int e = g - 512 * 256;
    int r = e >> 6, a = e & 63;
    w2T[e] = w2[a * 256 + r];
  }
}

// ---------------- generic tiled GEMM: C[t][r] = bias[r] + sum_k X[t][k]*W[r][woff+k]
__global__ void __launch_bounds__(256) gemm64(
    const float* __restrict__ X, int ldx,
    const float* __restrict__ W, int ldw, int woff,
    const float* __restrict__ bias,
    float* __restrict__ C, int crows, int K) {
  __shared__ float Xs[64 * 65];
  __shared__ float Ws[64 * 65];
  int t0 = blockIdx.x * 64, r0 = blockIdx.y * 64;
  int tid = threadIdx.x;
  int u = tid & 15, v = tid >> 4;
  float acc[4][4];
#pragma unroll
  for (int i = 0; i < 4; i++)
#pragma unroll
    for (int j = 0; j < 4; j++) acc[i][j] = 0.f;

  for (int kc = 0; kc < K; kc += 64) {
    for (int idx = tid; idx < 4096; idx += 256) {
      int row = idx >> 6, col = idx & 63;
      Xs[row * 65 + col] = X[(size_t)(t0 + row) * ldx + kc + col];
      Ws[row * 65 + col] = W[(size_t)(r0 + row) * ldw + woff + kc + col];
    }
    __syncthreads();
#pragma unroll 8
    for (int k = 0; k < 64; k++) {
      float xs[4], ws[4];
#pragma unroll
      for (int i = 0; i < 4; i++) xs[i] = Xs[(v + 16 * i) * 65 + k];
#pragma unroll
      for (int j = 0; j < 4; j++) ws[j] = Ws[(u + 16 * j) * 65 + k];
#pragma unroll
      for (int i = 0; i < 4; i++)
#pragma unroll
        for (int j = 0; j < 4; j++) acc[i][j] += xs[i] * ws[j];
    }
    __syncthreads();
  }
#pragma unroll
  for (int i = 0; i < 4; i++)
#pragma unroll
    for (int j = 0; j < 4; j++) {
      int t = t0 + v + 16 * i, r = r0 + u + 16 * j;
      C[(size_t)t * crows + r] = acc[i][j] + bias[r];
    }
}

// ---------------- fused sequential kernel (phase-1 recurrence + decoder GRU) --------
__global__ void __launch_bounds__(256) seq_kernel(
    const float* __restrict__ x_fix,    // [2048,64]
    const float* __restrict__ x_att,    // [2048,64,64]
    const float* __restrict__ w_ih,     // [768,1088]
    const float* __restrict__ w_hh,     // [768,256]
    const float* __restrict__ b_hh,     // [768]
    const float* __restrict__ q_hid_w,  // [256,832]
    const float* __restrict__ wqT,      // [512,256]
    const float* __restrict__ dwih,     // [768,576]
    const float* __restrict__ dwhh,     // [768,256]
    const float* __restrict__ dbih,     // [768]
    const float* __restrict__ dbhh,     // [768]
    const float* __restrict__ gi_fix,   // [2048,768] (bias+fix part of q-GRU gi)
    const float* __restrict__ hid_fix,  // [2048,256] (bias+fix part of q_hid)
    int* __restrict__ flags,
    float* __restrict__ h2x,    // [256]
    float* __restrict__ hidx,   // [256]
    float* __restrict__ qx,     // [512]
    float* __restrict__ dechx,  // [2][256]
    float* __restrict__ dava,   // [2048,512]
    float* __restrict__ dec_hist,  // [2048,256]
    float* __restrict__ out) {
  __shared__ float att_s[64 * 65];
  __shared__ __align__(16) float q_s[512];
  __shared__ __align__(16) float h_s[256];
  __shared__ __align__(16) float dech_s[256];
  __shared__ __align__(16) float attv_s[512];
  __shared__ float qk_s[512];       // holds attw after softmax
  __shared__ float attw0_s[512];
  __shared__ float aw_s[512];
  __shared__ __align__(16) float xcat_s[576];  // [fix(64) | dec_att_a(512)]
  __shared__ __align__(16) float hidf_s[256];
  __shared__ float g_s[4][8];
  __shared__ float dg_s[4][8];

  const int tid = threadIdx.x;
  const int bid = blockIdx.x;
  const int lane = tid & 63, wv = tid >> 6;

  // init state
  for (int i = tid; i < 512; i += 256) q_s[i] = 1.f;
  h_s[tid] = 0.f;
  dech_s[tid] = 0.f;
  __syncthreads();

  for (int t = 0; t < TT; ++t) {
    // ---------- segment 1: load tile, attention, q-GRU gates ----------
    const float* attg = x_att + (size_t)t * 4096;
    for (int idx = tid; idx < 4096; idx += 256)
      att_s[(idx >> 6) * 65 + (idx & 63)] = attg[idx];
    if (tid < 64) xcat_s[tid] = x_fix[t * 64 + tid];
    __syncthreads();

    // qk: logits[h][n]
    for (int h = wv; h < 8; h += 4) {
      float acc = 0.f;
#pragma unroll 8
      for (int a = 0; a < 64; a++) acc += q_s[h * 64 + a] * att_s[lane * 65 + a];
      qk_s[h * 64 + lane] = acc * 0.125f;
    }
    __syncthreads();
    // softmax over n per head (wave-wide)
    for (int h = wv; h < 8; h += 4) {
      float v = qk_s[h * 64 + lane];
      float m = warp_max(v);
      m = __shfl(m, 0, 64);
      float e = __expf(v - m);
      float s = warp_sum(e);
      s = __shfl(s, 0, 64);
      qk_s[h * 64 + lane] = e / s;
    }
    __syncthreads();
    if (bid == 0) {
      for (int i = tid; i < 512; i += 256)
        astore(&out[OUT_ATTW + (size_t)t * 512 + i], qk_s[i]);
    }
    if (t == 0) {
      for (int i = tid; i < 512; i += 256) attw0_s[i] = qk_s[i];
    }
    // att_v[h][a]
    for (int h = wv; h < 8; h += 4) {
      float acc = 0.f;
#pragma unroll 8
      for (int n = 0; n < 64; n++) acc += qk_s[h * 64 + n] * att_s[n * 65 + lane];
      attv_s[h * 64 + lane] = acc;
    }
    __syncthreads();

    // q-GRU gate rows: 24 rows for this block, 6 per wave
    {
      float accg[6], acch[6];
      int rows[6];
#pragma unroll
      for (int k = 0; k < 6; k++) {
        int m = wv + 4 * k;
        rows[k] = ((m >> 3) * 256) + bid * 8 + (m & 7);
        accg[k] = 0.f;
        acch[k] = 0.f;
      }
      const float4* av4 = (const float4*)attv_s;
      const float4* q4 = (const float4*)q_s;
#pragma unroll
      for (int c0 = 0; c0 < 2; c0++) {
        int c = lane + 64 * c0;
        float4 v1 = av4[c], v2 = q4[c];
#pragma unroll
        for (int k = 0; k < 6; k++) {
          const float4* Wav = (const float4*)(w_ih + (size_t)rows[k] * 1088 + 64);
          const float4* Wq = (const float4*)(w_ih + (size_t)rows[k] * 1088 + 576);
          accg[k] += dot4(Wav[c], v1) + dot4(Wq[c], v2);
        }
      }
      {
        const float4* h4 = (const float4*)h_s;
        float4 v3 = h4[lane];
#pragma unroll
        for (int k = 0; k < 6; k++) {
          const float4* Wh = (const float4*)(w_hh + (size_t)rows[k] * 256);
          acch[k] += dot4(Wh[lane], v3);
        }
      }
#pragma unroll
      for (int k = 0; k < 6; k++) {
        float gi = warp_sum(accg[k]);
        float gh = warp_sum(acch[k]);
        if (lane == 0) {
          int m = wv + 4 * k;
          int gate = m >> 3, i = m & 7;
          gi += gi_fix[(size_t)t * 768 + rows[k]];
          gh += b_hh[rows[k]];
          if (gate == 0) g_s[0][i] = gi + gh;
          else if (gate == 1) g_s[1][i] = gi + gh;
          else { g_s[2][i] = gi; g_s[3][i] = gh; }
        }
      }
    }
    __syncthreads();
    if (tid < 8) {
      float r = sigf(g_s[0][tid]), z = sigf(g_s[1][tid]);
      float nn = tanhf(g_s[2][tid] + r * g_s[3][tid]);
      float h2 = (1.f - z) * nn + z * h_s[bid * 8 + tid];
      astore(&h2x[bid * 8 + tid], h2);
    }
    gbar(flags, 3 * t + 0, bid);
    { int i = tid; h_s[i] = aload(&h2x[i]); }
    __syncthreads();

    // ---------- segment 2: q_hidden ----------
    {
      float acc[2] = {0.f, 0.f};
      const float4* h4 = (const float4*)h_s;
      const float4* av4 = (const float4*)attv_s;
      float4 vh = h4[lane];
#pragma unroll
      for (int k = 0; k < 2; k++) {
        int row = bid * 8 + wv + 4 * k;
        const float4* Qa = (const float4*)(q_hid_w + (size_t)row * 832);
        acc[k] += dot4(Qa[lane], vh);
      }
#pragma unroll
      for (int c0 = 0; c0 < 2; c0++) {
        int c = lane + 64 * c0;
        float4 va = av4[c];
#pragma unroll
        for (int k = 0; k < 2; k++) {
          int row = bid * 8 + wv + 4 * k;
          const float4* Qv = (const float4*)(q_hid_w + (size_t)row * 832 + 320);
          acc[k] += dot4(Qv[c], va);
        }
      }
#pragma unroll
      for (int k = 0; k < 2; k++) {
        float s = warp_sum(acc[k]);
        if (lane == 0) {
          int row = bid * 8 + wv + 4 * k;
          astore(&hidx[row], fmaxf(s + hid_fix[(size_t)t * 256 + row], 0.f));
        }
      }
    }
    gbar(flags, 3 * t + 1, bid);
    { int i = tid; hidf_s[i] = aload(&hidx[i]); }
    __syncthreads();

    // ---------- segment 3: query projection + decoder GRU step ----------
    {
      float acc[4] = {0.f, 0.f, 0.f, 0.f};
      const float4* hf4 = (const float4*)hidf_s;
      float4 v = hf4[lane];
#pragma unroll
      for (int k = 0; k < 4; k++) {
        int j = bid * 16 + wv + 4 * k;
        const float4* Wt = (const float4*)(wqT + (size_t)j * 256);
        acc[k] += dot4(Wt[lane], v);
      }
#pragma unroll
      for (int k = 0; k < 4; k++) {
        float s = warp_sum(acc[k]);
        if (lane == 0) astore(&qx[bid * 16 + wv + 4 * k], s);
      }
    }
    // decoder attention weights source
    if (t >= HZ) {
      for (int i = tid; i < 512; i += 256)
        aw_s[i] = aload(&out[OUT_ATTW + (size_t)(t - HZ) * 512 + i]);
    } else {
      for (int i = tid; i < 512; i += 256) aw_s[i] = attw0_s[i];
    }
    __syncthreads();
    // dec_att_a (redundant per block) into xcat_s[64..576)
    for (int h = wv; h < 8; h += 4) {
      float acc = 0.f;
#pragma unroll 8
      for (int n = 0; n < 64; n++) acc += aw_s[h * 64 + n] * att_s[n * 65 + lane];
      xcat_s[64 + h * 64 + lane] = acc;
    }
    __syncthreads();
    if (bid == 0) {
      for (int i = tid; i < 512; i += 256) dava[(size_t)t * 512 + i] = xcat_s[64 + i];
    }
    // decoder gates
    {
      float accg[6], acch[6];
      int rows[6];
#pragma unroll
      for (int k = 0; k < 6; k++) {
        int m = wv + 4 * k;
        rows[k] = ((m >> 3) * 256) + bid * 8 + (m & 7);
        accg[k] = 0.f;
        acch[k] = 0.f;
      }
      const float4* x4 = (const float4*)xcat_s;
#pragma unroll
      for (int c0 = 0; c0 < 3; c0++) {
        int c = lane + 64 * c0;
        if (c < 144) {
          float4 v = x4[c];
#pragma unroll
          for (int k = 0; k < 6; k++) {
            const float4* W = (const float4*)(dwih + (size_t)rows[k] * 576);
            accg[k] += dot4(W[c], v);
          }
        }
      }
      {
        const float4* dh4 = (const float4*)dech_s;
        float4 vh = dh4[lane];
#pragma unroll
        for (int k = 0; k < 6; k++) {
          const float4* Wh = (const float4*)(dwhh + (size_t)rows[k] * 256);
          acch[k] += dot4(Wh[lane], vh);
        }
      }
#pragma unroll
      for (int k = 0; k < 6; k++) {
        float gi = warp_sum(accg[k]);
        float gh = warp_sum(acch[k]);
        if (lane == 0) {
          int m = wv + 4 * k;
          int gate = m >> 3, i = m & 7;
          gi += dbih[rows[k]];
          gh += dbhh[rows[k]];
          if (gate == 0) dg_s[0][i] = gi + gh;
          else if (gate == 1) dg_s[1][i] = gi + gh;
          else { dg_s[2][i] = gi; dg_s[3][i] = gh; }
        }
      }
    }
    __syncthreads();
    if (tid < 8) {
      float r = sigf(dg_s[0][tid]), z = sigf(dg_s[1][tid]);
      float nn = tanhf(dg_s[2][tid] + r * dg_s[3][tid]);
      float h2 = (1.f - z) * nn + z * dech_s[bid * 8 + tid];
      astore(&dechx[(t & 1) * 256 + bid * 8 + tid], h2);
      dec_hist[(size_t)t * 256 + bid * 8 + tid] = h2;
    }
    gbar(flags, 3 * t + 2, bid);
    { int i = tid; dech_s[i] = aload(&dechx[(t & 1) * 256 + i]); }
    { int i = tid; q_s[i] = aload(&qx[i]); q_s[i + 256] = aload(&qx[i + 256]); }
    __syncthreads();
  }

  if (bid == 0) {
    out[OUT_QGRU + tid] = h_s[tid];
    out[OUT_DECGRU + tid] = dech_s[tid];
    for (int i = tid; i < 512; i += 256) out[OUT_QN + i] = q_s[i];
  }
}

// ---------------- feat assembly: [dec_h | x_fix | dec_att_a] ----------------
__global__ void featcopy(const float* __restrict__ dec_hist,
                         const float* __restrict__ x_fix,
                         const float* __restrict__ dava,
                         float* __restrict__ feat) {
  int t = blockIdx.x, tid = threadIdx.x;
  float* f = feat + (size_t)t * 832;
  f[tid] = dec_hist[(size_t)t * 256 + tid];
  if (tid < 64) f[256 + tid] = x_fix[t * 64 + tid];
  for (int i = tid; i < 512; i += 256) f[320 + i] = dava[(size_t)t * 512 + i];
}

// ---------------- final MLP: per (t,n) hid=relu(s_t + W1a@att_n); pred=relu(W2@hid+b2)
__global__ void __launch_bounds__(256) final_k(
    const float* __restrict__ x_att,
    const float* __restrict__ s,      // [2048,256] shared part incl. b1
    const float* __restrict__ w1,     // dec_hid_w [256,896]
    const float* __restrict__ w2T,    // [256,64]
    const float* __restrict__ b2,     // [64]
    float* __restrict__ pred) {
  __shared__ float att_s[4096];
  __shared__ float s_s[256];
  __shared__ float hid_s[32 * 256];
  int t = blockIdx.x, tid = threadIdx.x, lane = tid & 63, wv = tid >> 6;
  for (int i = tid; i < 4096; i += 256) att_s[i] = x_att[(size_t)t * 4096 + i];
  s_s[tid] = s[(size_t)t * 256 + tid];
  float4 w1v[16];
  const float4* W1a4 = (const float4*)(w1 + (size_t)tid * 896 + 832);
#pragma unroll
  for (int q = 0; q < 16; q++) w1v[q] = W1a4[q];
  float bb = b2[lane];
  __syncthreads();
  for (int ch = 0; ch < 2; ch++) {
    for (int nl = 0; nl < 32; nl++) {
      int n = ch * 32 + nl;
      const float4* a4 = (const float4*)(att_s + n * 64);
      float acc = s_s[tid];
#pragma unroll
      for (int q = 0; q < 16; q++) acc += dot4(w1v[q], a4[q]);
      hid_s[nl * 256 + tid] = fmaxf(acc, 0.f);
    }
    __syncthreads();
    float accb[8];
#pragma unroll
    for (int j = 0; j < 8; j++) accb[j] = bb;
    for (int r = 0; r < 256; r++) {
      float w = w2T[r * 64 + lane];
#pragma unroll
      for (int j = 0; j < 8; j++) accb[j] += w * hid_s[(wv * 8 + j) * 256 + r];
    }
#pragma unroll
    for (int j = 0; j < 8; j++) {
      int n = ch * 32 + wv * 8 + j;
      pred[(size_t)t * 4096 + n * 64 + lane] = fmaxf(accb[j], 0.f);
    }
    __syncthreads();
  }
}

extern "C" void kernel_launch(void* const* d_in, const int* in_sizes, int n_in,
                              void* d_out, int out_size, void* d_ws, size_t ws_size,
                              hipStream_t stream) {
  const float* x_fix = (const float*)d_in[0];
  const float* x_att = (const float*)d_in[1];
  // d_in[2] = train_horizon (16), fixed by problem definition
  const float* qwih = (const float*)d_in[3];
  const float* qwhh = (const float*)d_in[4];
  const float* qbih = (const float*)d_in[5];
  const float* qbhh = (const float*)d_in[6];
  const float* qhw = (const float*)d_in[7];
  const float* qhb = (const float*)d_in[8];
  const float* wq = (const float*)d_in[9];
  const float* dwih = (const float*)d_in[10];
  const float* dwhh = (const float*)d_in[11];
  const float* dbih = (const float*)d_in[12];
  const float* dbhh = (const float*)d_in[13];
  const float* w1 = (const float*)d_in[14];
  const float* b1 = (const float*)d_in[15];
  const float* w2 = (const float*)d_in[16];
  const float* b2 = (const float*)d_in[17];
  float* out = (float*)d_out;

  char* ws = (char*)d_ws;
  int* flags = (int*)(ws + WSO_FLAGS);
  float* h2x = (float*)(ws + WSO_H2X);
  float* hidx = (float*)(ws + WSO_HIDX);
  float* qx = (float*)(ws + WSO_QX);
  float* dechx = (float*)(ws + WSO_DECHX);
  float* gi_fix = (float*)(ws + WSO_GIFIX);
  float* hid_fix = (float*)(ws + WSO_HIDFIX);
  float* wqT = (float*)(ws + WSO_WQT);
  float* w2T = (float*)(ws + WSO_W2T);
  float* dava = (float*)(ws + WSO_DAVA);
  float* dec_hist = (float*)(ws + WSO_DECH);
  float* feat = (float*)(ws + WSO_FEAT);
  float* sbuf = (float*)(ws + WSO_S);

  // zero barrier flags (+ exchange buffers) — required every launch
  hipMemsetAsync(ws, 0, WSO_ZEND, stream);

  transpose_k<<<576, 256, 0, stream>>>(wq, w2, wqT, w2T);
  // gi_fix = b_ih + W_ih[:, :64] @ x_fix^T   (per t)
  gemm64<<<dim3(32, 12), 256, 0, stream>>>(x_fix, 64, qwih, 1088, 0, qbih,
                                           gi_fix, 768, 64);
  // hid_fix = q_hid_b + q_hid_w[:, 256:320] @ x_fix^T
  gemm64<<<dim3(32, 4), 256, 0, stream>>>(x_fix, 64, qhw, 832, 256, qhb,
                                          hid_fix, 256, 64);

  seq_kernel<<<NBLK, 256, 0, stream>>>(x_fix, x_att, qwih, qwhh, qbhh, qhw, wqT,
                                       dwih, dwhh, dbih, dbhh, gi_fix, hid_fix,
                                       flags, h2x, hidx, qx, dechx, dava,
                                       dec_hist, out);

  featcopy<<<2048, 256, 0, stream>>>(dec_hist, x_fix, dava, feat);
  // s = b1 + W1[:, :832] @ feat^T
  gemm64<<<dim3(32, 4), 256, 0, stream>>>(feat, 832, w1, 896, 0, b1,
                                          sbuf, 256, 832);
  final_k<<<2048, 256, 0, stream>>>(x_att, sbuf, w1, w2T, b2, out);
}

// Round 2
// 38043.030 us; speedup vs baseline: 1.5828x; 1.5828x over previous
//
#include <hip/hip_runtime.h>
#include <math.h>

// Problem constants
#define TT 2048
#define HZ 16
#define NBLK 32

// d_out layout (floats): pred | attw | q_gru_n | dec_gru_n | query_n
#define OUT_ATTW   (2048*64*64)            // 8388608
#define OUT_QGRU   (OUT_ATTW + 2048*8*64)  // 9437184
#define OUT_DECGRU (OUT_QGRU + 256)        // 9437440
#define OUT_QN     (OUT_DECGRU + 256)      // 9437696

// d_ws layout (bytes)
#define WSO_FLAGS  0                        // int[32*32] padded flags (4096 B)
#define WSO_H2X    4096                     // float[256]
#define WSO_DECHX  5120                     // float[256]
#define WSO_QX     6144                     // float[2][512]
#define WSO_ZEND   10240                    // end of memset region
#define WSO_GIFIX  10240                    // float[2048][768]
#define WSO_HIDFIX (WSO_GIFIX + 2048*768*4)
#define WSO_WQT    (WSO_HIDFIX + 2048*256*4)
#define WSO_W2T    (WSO_WQT + 512*256*4)
#define WSO_DAVA   (WSO_W2T + 64*256*4)
#define WSO_DECH   (WSO_DAVA + 2048*512*4)
#define WSO_FEAT   (WSO_DECH + 2048*256*4)
#define WSO_S      (WSO_FEAT + 2048*832*4)

__device__ __forceinline__ float warp_sum(float v) {
#pragma unroll
  for (int o = 32; o > 0; o >>= 1) v += __shfl_down(v, o, 64);
  return v;
}
__device__ __forceinline__ float warp_max(float v) {
#pragma unroll
  for (int o = 32; o > 0; o >>= 1) v = fmaxf(v, __shfl_down(v, o, 64));
  return v;
}
__device__ __forceinline__ float sigf(float x) { return 1.f / (1.f + __expf(-x)); }
__device__ __forceinline__ float dot4(float4 a, float4 b) {
  return a.x*b.x + a.y*b.y + a.z*b.z + a.w*b.w;
}
__device__ __forceinline__ float aload(const float* p) {
  return __hip_atomic_load(p, __ATOMIC_RELAXED, __HIP_MEMORY_SCOPE_AGENT);
}
__device__ __forceinline__ void astore(float* p, float v) {
  __hip_atomic_store(p, v, __ATOMIC_RELAXED, __HIP_MEMORY_SCOPE_AGENT);
}

// Inter-block barrier: per-block monotonic phase counter, each in its own
// 128B line. Wave 0 spins; everyone else waits at __syncthreads.
__device__ __forceinline__ void gbar(int* flags, int phase, int bid) {
  __syncthreads();
  if (threadIdx.x == 0) {
    __builtin_amdgcn_fence(__ATOMIC_RELEASE, "agent");
    __hip_atomic_store(&flags[bid * 32], phase, __ATOMIC_RELAXED,
                       __HIP_MEMORY_SCOPE_AGENT);
  }
  if (threadIdx.x < 64) {
    int l = threadIdx.x;
    int done = 0;
    while (!done) {
      int f = phase;
      if (l < NBLK)
        f = __hip_atomic_load(&flags[l * 32], __ATOMIC_RELAXED,
                              __HIP_MEMORY_SCOPE_AGENT);
      done = __all(f >= phase);
      if (!done) __builtin_amdgcn_s_sleep(1);
    }
  }
  __syncthreads();
  __builtin_amdgcn_fence(__ATOMIC_ACQUIRE, "agent");
}

// ---------------- transpose of weight_q and dec_out_w ----------------
__global__ void transpose_k(const float* __restrict__ wq,   // [256,512]
                            const float* __restrict__ w2,   // [64,256]
                            float* __restrict__ wqT,        // [512,256]
                            float* __restrict__ w2T) {      // [256,64]
  int g = blockIdx.x * 256 + threadIdx.x;
  if (blockIdx.x < 512) {
    int j = g >> 8, c = g & 255;
    wqT[g] = wq[c * 512 + j];
  } else {
    int e = g - 512 * 256;
    int r = e >> 6, a = e & 63;
    w2T[e] = w2[a * 256 + r];
  }
}

// ---------------- generic tiled GEMM: C[t][r] = bias[r] + sum_k X[t][k]*W[r][woff+k]
__global__ void __launch_bounds__(256) gemm64(
    const float* __restrict__ X, int ldx,
    const float* __restrict__ W, int ldw, int woff,
    const float* __restrict__ bias,
    float* __restrict__ C, int crows, int K) {
  __shared__ float Xs[64 * 65];
  __shared__ float Ws[64 * 65];
  int t0 = blockIdx.x * 64, r0 = blockIdx.y * 64;
  int tid = threadIdx.x;
  int u = tid & 15, v = tid >> 4;
  float acc[4][4];
#pragma unroll
  for (int i = 0; i < 4; i++)
#pragma unroll
    for (int j = 0; j < 4; j++) acc[i][j] = 0.f;

  for (int kc = 0; kc < K; kc += 64) {
    for (int idx = tid; idx < 4096; idx += 256) {
      int row = idx >> 6, col = idx & 63;
      Xs[row * 65 + col] = X[(size_t)(t0 + row) * ldx + kc + col];
      Ws[row * 65 + col] = W[(size_t)(r0 + row) * ldw + woff + kc + col];
    }
    __syncthreads();
#pragma unroll 8
    for (int k = 0; k < 64; k++) {
      float xs[4], ws[4];
#pragma unroll
      for (int i = 0; i < 4; i++) xs[i] = Xs[(v + 16 * i) * 65 + k];
#pragma unroll
      for (int j = 0; j < 4; j++) ws[j] = Ws[(u + 16 * j) * 65 + k];
#pragma unroll
      for (int i = 0; i < 4; i++)
#pragma unroll
        for (int j = 0; j < 4; j++) acc[i][j] += xs[i] * ws[j];
    }
    __syncthreads();
  }
#pragma unroll
  for (int i = 0; i < 4; i++)
#pragma unroll
    for (int j = 0; j < 4; j++) {
      int t = t0 + v + 16 * i, r = r0 + u + 16 * j;
      C[(size_t)t * crows + r] = acc[i][j] + bias[r];
    }
}

// ---------------- fused sequential kernel: 2 barriers/step ----------------
__global__ void __launch_bounds__(256) seq_kernel(
    const float* __restrict__ x_fix,    // [2048,64]
    const float* __restrict__ x_att,    // [2048,64,64]
    const float* __restrict__ w_ih,     // [768,1088]
    const float* __restrict__ w_hh,     // [768,256]
    const float* __restrict__ b_hh,     // [768]
    const float* __restrict__ q_hid_w,  // [256,832]
    const float* __restrict__ wqT,      // [512,256]
    const float* __restrict__ dwih,     // [768,576]
    const float* __restrict__ dwhh,     // [768,256]
    const float* __restrict__ dbih,     // [768]
    const float* __restrict__ dbhh,     // [768]
    const float* __restrict__ gi_fix,   // [2048,768]
    const float* __restrict__ hid_fix,  // [2048,256]
    int* __restrict__ flags,
    float* __restrict__ h2x,    // [256]
    float* __restrict__ dechx,  // [256]
    float* __restrict__ qx,     // [2][512]
    float* __restrict__ dava,   // [2048,512]
    float* __restrict__ dec_hist,  // [2048,256]
    float* __restrict__ out) {
  __shared__ float att_s[64 * 65];           // x_att tile (t)
  __shared__ float ring_s[16][512];          // attw ring, slot t%16
  __shared__ __align__(16) float q_s[512];
  __shared__ __align__(16) float h_s[256];
  __shared__ __align__(16) float dech_s[256];
  __shared__ __align__(16) float attv_s[512];
  __shared__ float qk_s[512];
  __shared__ __align__(16) float xcat_s[576];  // [fix(64) | dec_att_a(512)]
  __shared__ float hid8_s[8];
  __shared__ float g_s[4][8];
  __shared__ float dg_s[4][8];

  const int tid = threadIdx.x;
  const int bid = blockIdx.x;
  const int lane = tid & 63, wv = tid >> 6;
  const int h0 = wv * 2;

  // init state + initial tile
  for (int i = tid; i < 512; i += 256) q_s[i] = 1.f;
  h_s[tid] = 0.f;
  dech_s[tid] = 0.f;
  for (int idx = tid; idx < 4096; idx += 256)
    att_s[(idx >> 6) * 65 + (idx & 63)] = x_att[idx];
  __syncthreads();

  for (int t = 0; t < TT; ++t) {
    const int p = t & 1;
    // ================= segment A =================
    if (tid < 64) xcat_s[tid] = x_fix[t * 64 + tid];
    // QK logits: wave wv owns heads h0, h0+1; lane = n
    {
      float acc0 = 0.f, acc1 = 0.f;
#pragma unroll 16
      for (int a = 0; a < 64; a++) {
        float xv = att_s[lane * 65 + a];
        acc0 += q_s[h0 * 64 + a] * xv;
        acc1 += q_s[h0 * 64 + 64 + a] * xv;
      }
      qk_s[h0 * 64 + lane] = acc0 * 0.125f;
      qk_s[h0 * 64 + 64 + lane] = acc1 * 0.125f;
    }
    __syncthreads();
    // softmax per head across the 64 lanes
#pragma unroll
    for (int hh = 0; hh < 2; hh++) {
      int h = h0 + hh;
      float v = qk_s[h * 64 + lane];
      float m = warp_max(v); m = __shfl(m, 0, 64);
      float e = __expf(v - m);
      float s = warp_sum(e); s = __shfl(s, 0, 64);
      qk_s[h * 64 + lane] = e / s;
    }
    __syncthreads();
    if (t == 0) {
      for (int i = tid; i < 512; i += 256) ring_s[0][i] = qk_s[i];
      __syncthreads();
    }
    // attw output (16 elements per block, distributed)
    if (tid < 16) out[OUT_ATTW + (size_t)t * 512 + bid * 16 + tid] =
        qk_s[bid * 16 + tid];
    // att_v + dec_att_a (lane = a); ring slot holds attw(t-16) (or attw(0))
    {
      const int slot = (t >= 16) ? (t & 15) : 0;
      const float* rg = ring_s[slot];
      float av0 = 0.f, av1 = 0.f, dv0 = 0.f, dv1 = 0.f;
#pragma unroll 8
      for (int n = 0; n < 64; n++) {
        float xv = att_s[n * 65 + lane];
        av0 += qk_s[h0 * 64 + n] * xv;
        av1 += qk_s[h0 * 64 + 64 + n] * xv;
        dv0 += rg[h0 * 64 + n] * xv;
        dv1 += rg[h0 * 64 + 64 + n] * xv;
      }
      attv_s[h0 * 64 + lane] = av0;
      attv_s[h0 * 64 + 64 + lane] = av1;
      xcat_s[64 + h0 * 64 + lane] = dv0;
      xcat_s[64 + h0 * 64 + 64 + lane] = dv1;
    }
    __syncthreads();
    // dava output (16/block) + ring write of attw(t)
    if (tid < 16) dava[(size_t)t * 512 + bid * 16 + tid] =
        xcat_s[64 + bid * 16 + tid];
    if (t > 0) {
      for (int i = tid; i < 512; i += 256) ring_s[t & 15][i] = qk_s[i];
    }
    // q-GRU gates: 24 rows/block, 6/wave
    {
      float accg[6], acch[6];
      int rows[6];
#pragma unroll
      for (int k = 0; k < 6; k++) {
        int m = wv + 4 * k;
        rows[k] = ((m >> 3) * 256) + bid * 8 + (m & 7);
        accg[k] = 0.f; acch[k] = 0.f;
      }
      const float4* av4 = (const float4*)attv_s;
      const float4* q4 = (const float4*)q_s;
#pragma unroll
      for (int c0 = 0; c0 < 2; c0++) {
        int c = lane + 64 * c0;
        float4 v1 = av4[c], v2 = q4[c];
#pragma unroll
        for (int k = 0; k < 6; k++) {
          const float4* Wav = (const float4*)(w_ih + (size_t)rows[k] * 1088 + 64);
          const float4* Wq = (const float4*)(w_ih + (size_t)rows[k] * 1088 + 576);
          accg[k] += dot4(Wav[c], v1) + dot4(Wq[c], v2);
        }
      }
      {
        const float4* h4 = (const float4*)h_s;
        float4 v3 = h4[lane];
#pragma unroll
        for (int k = 0; k < 6; k++) {
          const float4* Wh = (const float4*)(w_hh + (size_t)rows[k] * 256);
          acch[k] += dot4(Wh[lane], v3);
        }
      }
#pragma unroll
      for (int k = 0; k < 6; k++) {
        float gi = warp_sum(accg[k]);
        float gh = warp_sum(acch[k]);
        if (lane == 0) {
          int m = wv + 4 * k;
          int gate = m >> 3, i = m & 7;
          gi += gi_fix[(size_t)t * 768 + rows[k]];
          gh += b_hh[rows[k]];
          if (gate == 0) g_s[0][i] = gi + gh;
          else if (gate == 1) g_s[1][i] = gi + gh;
          else { g_s[2][i] = gi; g_s[3][i] = gh; }
        }
      }
    }
    // decoder gates: 24 rows/block, 6/wave
    {
      float accg[6], acch[6];
      int rows[6];
#pragma unroll
      for (int k = 0; k < 6; k++) {
        int m = wv + 4 * k;
        rows[k] = ((m >> 3) * 256) + bid * 8 + (m & 7);
        accg[k] = 0.f; acch[k] = 0.f;
      }
      const float4* x4 = (const float4*)xcat_s;
#pragma unroll
      for (int c0 = 0; c0 < 3; c0++) {
        int c = lane + 64 * c0;
        if (c < 144) {
          float4 v = x4[c];
#pragma unroll
          for (int k = 0; k < 6; k++) {
            const float4* W = (const float4*)(dwih + (size_t)rows[k] * 576);
            accg[k] += dot4(W[c], v);
          }
        }
      }
      {
        const float4* dh4 = (const float4*)dech_s;
        float4 vh = dh4[lane];
#pragma unroll
        for (int k = 0; k < 6; k++) {
          const float4* Wh = (const float4*)(dwhh + (size_t)rows[k] * 256);
          acch[k] += dot4(Wh[lane], vh);
        }
      }
#pragma unroll
      for (int k = 0; k < 6; k++) {
        float gi = warp_sum(accg[k]);
        float gh = warp_sum(acch[k]);
        if (lane == 0) {
          int m = wv + 4 * k;
          int gate = m >> 3, i = m & 7;
          gi += dbih[rows[k]];
          gh += dbhh[rows[k]];
          if (gate == 0) dg_s[0][i] = gi + gh;
          else if (gate == 1) dg_s[1][i] = gi + gh;
          else { dg_s[2][i] = gi; dg_s[3][i] = gh; }
        }
      }
    }
    __syncthreads();
    if (tid < 8) {
      float r = sigf(g_s[0][tid]), z = sigf(g_s[1][tid]);
      float nn = tanhf(g_s[2][tid] + r * g_s[3][tid]);
      float h2 = (1.f - z) * nn + z * h_s[bid * 8 + tid];
      astore(&h2x[bid * 8 + tid], h2);
    }
    if (tid >= 64 && tid < 72) {
      int i = tid - 64;
      float r = sigf(dg_s[0][i]), z = sigf(dg_s[1][i]);
      float nn = tanhf(dg_s[2][i] + r * dg_s[3][i]);
      float h2 = (1.f - z) * nn + z * dech_s[bid * 8 + i];
      astore(&dechx[bid * 8 + i], h2);
      dec_hist[(size_t)t * 256 + bid * 8 + i] = h2;  // post-kernel consumer
    }
    gbar(flags, 2 * t + 1, bid);
    // ================= segment B =================
    h_s[tid] = aload(&h2x[tid]);
    dech_s[tid] = aload(&dechx[tid]);
    // prefetch x_att tile (t+1) into registers
    float4 pf[4];
    {
      int tn = (t + 1 < TT) ? t + 1 : TT - 1;
      const float4* g = (const float4*)(x_att + (size_t)tn * 4096);
#pragma unroll
      for (int j = 0; j < 4; j++) pf[j] = g[tid * 4 + j];
    }
    __syncthreads();
    // hid rows (8/block, 2/wave): relu(qhw[:,0:256]@h2 + qhw[:,320:832]@attv + fixpart)
#pragma unroll
    for (int rr = 0; rr < 2; rr++) {
      int r = wv * 2 + rr;
      int row = bid * 8 + r;
      const float4* W = (const float4*)(q_hid_w + (size_t)row * 832);
      float acc = dot4(W[lane], ((const float4*)h_s)[lane]);
      acc += dot4(W[80 + lane], ((const float4*)attv_s)[lane]);
      acc += dot4(W[144 + lane], ((const float4*)attv_s)[64 + lane]);
      float s = warp_sum(acc);
      if (lane == 0) hid8_s[r] = fmaxf(s + hid_fix[(size_t)t * 256 + row], 0.f);
    }
    __syncthreads();
    // partial query: qpart[j] = sum_r hid8[r] * wqT[j][bid*8+r], atomicAdd
    {
      float hv[8];
#pragma unroll
      for (int r = 0; r < 8; r++) hv[r] = hid8_s[r];
#pragma unroll
      for (int jj = 0; jj < 2; jj++) {
        int j = tid * 2 + jj;
        const float* Wq = wqT + (size_t)j * 256 + bid * 8;
        float acc = 0.f;
#pragma unroll
        for (int r = 0; r < 8; r++) acc += hv[r] * Wq[r];
        __hip_atomic_fetch_add(&qx[p * 512 + j], acc, __ATOMIC_RELAXED,
                               __HIP_MEMORY_SCOPE_AGENT);
      }
      if (tid < 16) astore(&qx[(1 - p) * 512 + bid * 16 + tid], 0.f);
    }
    // deposit prefetched tile(t+1) into att_s (att_s dead since segment A)
    {
      int row = tid >> 2, c0 = (tid & 3) * 16;
#pragma unroll
      for (int j = 0; j < 4; j++) {
        float4 v = pf[j];
        float* d = &att_s[row * 65 + c0 + j * 4];
        d[0] = v.x; d[1] = v.y; d[2] = v.z; d[3] = v.w;
      }
    }
    gbar(flags, 2 * t + 2, bid);
    for (int i = tid; i < 512; i += 256) q_s[i] = aload(&qx[p * 512 + i]);
    __syncthreads();
  }

  if (bid == 0) {
    out[OUT_QGRU + tid] = h_s[tid];
    out[OUT_DECGRU + tid] = dech_s[tid];
    for (int i = tid; i < 512; i += 256) out[OUT_QN + i] = q_s[i];
  }
}

// ---------------- feat assembly: [dec_h | x_fix | dec_att_a] ----------------
__global__ void featcopy(const float* __restrict__ dec_hist,
                         const float* __restrict__ x_fix,
                         const float* __restrict__ dava,
                         float* __restrict__ feat) {
  int t = blockIdx.x, tid = threadIdx.x;
  float* f = feat + (size_t)t * 832;
  f[tid] = dec_hist[(size_t)t * 256 + tid];
  if (tid < 64) f[256 + tid] = x_fix[t * 64 + tid];
  for (int i = tid; i < 512; i += 256) f[320 + i] = dava[(size_t)t * 512 + i];
}

// ---------------- final MLP ----------------
__global__ void __launch_bounds__(256) final_k(
    const float* __restrict__ x_att,
    const float* __restrict__ s,      // [2048,256] shared part incl. b1
    const float* __restrict__ w1,     // dec_hid_w [256,896]
    const float* __restrict__ w2T,    // [256,64]
    const float* __restrict__ b2,     // [64]
    float* __restrict__ pred) {
  __shared__ float att_s[4096];
  __shared__ float s_s[256];
  __shared__ float hid_s[32 * 256];
  int t = blockIdx.x, tid = threadIdx.x, lane = tid & 63, wv = tid >> 6;
  for (int i = tid; i < 4096; i += 256) att_s[i] = x_att[(size_t)t * 4096 + i];
  s_s[tid] = s[(size_t)t * 256 + tid];
  float4 w1v[16];
  const float4* W1a4 = (const float4*)(w1 + (size_t)tid * 896 + 832);
#pragma unroll
  for (int q = 0; q < 16; q++) w1v[q] = W1a4[q];
  float bb = b2[lane];
  __syncthreads();
  for (int ch = 0; ch < 2; ch++) {
    for (int nl = 0; nl < 32; nl++) {
      int n = ch * 32 + nl;
      const float4* a4 = (const float4*)(att_s + n * 64);
      float acc = s_s[tid];
#pragma unroll
      for (int q = 0; q < 16; q++) acc += dot4(w1v[q], a4[q]);
      hid_s[nl * 256 + tid] = fmaxf(acc, 0.f);
    }
    __syncthreads();
    float accb[8];
#pragma unroll
    for (int j = 0; j < 8; j++) accb[j] = bb;
    for (int r = 0; r < 256; r++) {
      float w = w2T[r * 64 + lane];
#pragma unroll
      for (int j = 0; j < 8; j++) accb[j] += w * hid_s[(wv * 8 + j) * 256 + r];
    }
#pragma unroll
    for (int j = 0; j < 8; j++) {
      int n = ch * 32 + wv * 8 + j;
      pred[(size_t)t * 4096 + n * 64 + lane] = fmaxf(accb[j], 0.f);
    }
    __syncthreads();
  }
}

extern "C" void kernel_launch(void* const* d_in, const int* in_sizes, int n_in,
                              void* d_out, int out_size, void* d_ws, size_t ws_size,
                              hipStream_t stream) {
  const float* x_fix = (const float*)d_in[0];
  const float* x_att = (const float*)d_in[1];
  const float* qwih = (const float*)d_in[3];
  const float* qwhh = (const float*)d_in[4];
  const float* qbih = (const float*)d_in[5];
  const float* qbhh = (const float*)d_in[6];
  const float* qhw = (const float*)d_in[7];
  const float* qhb = (const float*)d_in[8];
  const float* wq = (const float*)d_in[9];
  const float* dwih = (const float*)d_in[10];
  const float* dwhh = (const float*)d_in[11];
  const float* dbih = (const float*)d_in[12];
  const float* dbhh = (const float*)d_in[13];
  const float* w1 = (const float*)d_in[14];
  const float* b1 = (const float*)d_in[15];
  const float* w2 = (const float*)d_in[16];
  const float* b2 = (const float*)d_in[17];
  float* out = (float*)d_out;

  char* ws = (char*)d_ws;
  int* flags = (int*)(ws + WSO_FLAGS);
  float* h2x = (float*)(ws + WSO_H2X);
  float* dechx = (float*)(ws + WSO_DECHX);
  float* qx = (float*)(ws + WSO_QX);
  float* gi_fix = (float*)(ws + WSO_GIFIX);
  float* hid_fix = (float*)(ws + WSO_HIDFIX);
  float* wqT = (float*)(ws + WSO_WQT);
  float* w2T = (float*)(ws + WSO_W2T);
  float* dava = (float*)(ws + WSO_DAVA);
  float* dec_hist = (float*)(ws + WSO_DECH);
  float* feat = (float*)(ws + WSO_FEAT);
  float* sbuf = (float*)(ws + WSO_S);

  // zero barrier flags + exchange buffers — required every launch
  hipMemsetAsync(ws, 0, WSO_ZEND, stream);

  transpose_k<<<576, 256, 0, stream>>>(wq, w2, wqT, w2T);
  gemm64<<<dim3(32, 12), 256, 0, stream>>>(x_fix, 64, qwih, 1088, 0, qbih,
                                           gi_fix, 768, 64);
  gemm64<<<dim3(32, 4), 256, 0, stream>>>(x_fix, 64, qhw, 832, 256, qhb,
                                          hid_fix, 256, 64);

  seq_kernel<<<NBLK, 256, 0, stream>>>(x_fix, x_att, qwih, qwhh, qbhh, qhw, wqT,
                                       dwih, dwhh, dbih, dbhh, gi_fix, hid_fix,
                                       flags, h2x, dechx, qx, dava,
                                       dec_hist, out);

  featcopy<<<2048, 256, 0, stream>>>(dec_hist, x_fix, dava, feat);
  gemm64<<<dim3(32, 4), 256, 0, stream>>>(feat, 832, w1, 896, 0, b1,
                                          sbuf, 256, 832);
  final_k<<<2048, 256, 0, stream>>>(x_att, sbuf, w1, w2T, b2, out);
}